// Round 2
// baseline (1087.148 us; speedup 1.0000x reference)
//
#include <hip/hip_runtime.h>

// Problem constants
#define BATCH 1024
#define TT 48          // inst columns
#define NSTEP 47       // scan steps
#define VOC 2001       // V+1
#define RNN 64
#define NOBJ 25
#define NROWS (BATCH*NSTEP)   // 48128
#define NTILE 126             // ceil(2016/16)
#define NPAD 2016

typedef _Float16 h2 __attribute__((ext_vector_type(2)));
typedef _Float16 h8 __attribute__((ext_vector_type(8)));
typedef short short8 __attribute__((ext_vector_type(8)));
typedef float f32x4 __attribute__((ext_vector_type(4)));

__device__ __forceinline__ float fdot2f(h2 a, h2 b, float c){
#if __has_builtin(__builtin_amdgcn_fdot2)
    return __builtin_amdgcn_fdot2(a, b, c, false);
#else
    return c + (float)a[0]*(float)b[0] + (float)a[1]*(float)b[1];
#endif
}

__device__ __forceinline__ float dot8(h8 w, h8 x, float acc){
    acc = fdot2f(__builtin_shufflevector(w,w,0,1), __builtin_shufflevector(x,x,0,1), acc);
    acc = fdot2f(__builtin_shufflevector(w,w,2,3), __builtin_shufflevector(x,x,2,3), acc);
    acc = fdot2f(__builtin_shufflevector(w,w,4,5), __builtin_shufflevector(x,x,4,5), acc);
    acc = fdot2f(__builtin_shufflevector(w,w,6,7), __builtin_shufflevector(x,x,6,7), acc);
    return acc;
}

__device__ __forceinline__ float sigf(float x){ return 1.f/(1.f+__expf(-x)); }
__device__ __forceinline__ float tanh_(float x){
    float e = __expf(2.f*fminf(x, 15.f));   // clamp avoids inf/inf NaN
    return (e-1.f)/(e+1.f);
}
__device__ __forceinline__ unsigned short bf16r(float f){
    unsigned u = __float_as_uint(f);
    return (unsigned short)((u + 0x7FFFu + ((u>>16)&1u)) >> 16);
}

// LDS-only barrier: publishes ds_writes (lgkmcnt) but does NOT drain vmcnt,
// so embW prefetch / h_hist stores pipeline across it. No cross-thread
// communication through global memory happens inside the recurrent loop.
__device__ __forceinline__ void block_sync_lds(){
    asm volatile("s_waitcnt lgkmcnt(0)" ::: "memory");
    __builtin_amdgcn_s_barrier();
    asm volatile("" ::: "memory");
}

// ---------------------------------------------------------------- prep kernels

// diff_canvas + time-invariant attention terms pre1/pre2 [B,25,32]
__global__ void k_pre(const float* __restrict__ prev, const float* __restrict__ fin,
                      const float* __restrict__ a1w1, const float* __restrict__ a1b1,
                      const float* __restrict__ a2w1, const float* __restrict__ a2b1,
                      float* __restrict__ diff, float* __restrict__ pre1, float* __restrict__ pre2){
    int idx = blockIdx.x*256 + threadIdx.x;
    if (idx >= BATCH*NOBJ) return;
    float p0 = prev[idx*4+0], p1 = prev[idx*4+1], p2 = prev[idx*4+2], p3 = prev[idx*4+3];
    bool masked = (p0+p1+p2+p3) > 0.f;
    float d0 = masked ? -1.f : fin[idx*4+0];
    float d1 = masked ? -1.f : fin[idx*4+1];
    float d2 = masked ? -1.f : fin[idx*4+2];
    float d3 = masked ? -1.f : fin[idx*4+3];
    diff[idx*4+0]=d0; diff[idx*4+1]=d1; diff[idx*4+2]=d2; diff[idx*4+3]=d3;
    for (int j=0;j<32;++j){
        const float* w1 = a1w1 + j*68 + 64;
        const float* w2 = a2w1 + j*68 + 64;
        pre1[idx*32+j] = a1b1[j] + d0*w1[0] + d1*w1[1] + d2*w1[2] + d3*w1[3];
        pre2[idx*32+j] = a2b1[j] + p0*w2[0] + p1*w2[1] + p2*w2[2] + p3*w2[3];
    }
}

// embW[v][g] = b_ih_att[g]+b_hh_att[g] + sum_k embed[v][k]*W_ih_att[g][64+k]
__global__ void k_embw(const float* __restrict__ embed, const float* __restrict__ Wia,
                       const float* __restrict__ bia, const float* __restrict__ bha,
                       float* __restrict__ embW){
    int v = blockIdx.x, g = threadIdx.x;
    __shared__ float er[64];
    if (g < 64) er[g] = embed[v*64+g];
    __syncthreads();
    float acc = bia[g] + bha[g];
    const float* wr = Wia + g*128 + 64;
    #pragma unroll 8
    for (int k=0;k<64;++k) acc += er[k]*wr[k];
    embW[v*256+g] = acc;
}

// pack fp32 weight rows [G][srcK] cols koff..koff+K-1 -> f16 row-major [G][K]
__global__ void k_packrow(const float* __restrict__ src, _Float16* __restrict__ dst,
                          int srcK, int koff, int K, int total){
    int idx = blockIdx.x*256 + threadIdx.x;
    if (idx >= total) return;
    int k = idx % K, g = idx / K;
    dst[idx] = (_Float16)src[g*srcK + koff + k];
}

// Weff[g][m] = sum_d W_ih_lang[g][d]*tw2[d][m]; biasL2[g] = bil+bhl+sum_d W[g][d]*tb2[d]
__global__ void k_weff(const float* __restrict__ Wil, const float* __restrict__ tw2,
                       const float* __restrict__ tb2, const float* __restrict__ bil,
                       const float* __restrict__ bhl, _Float16* __restrict__ Weff,
                       float* __restrict__ biasL2){
    __shared__ float t2[64*32];
    int g = threadIdx.x;
    for (int i=g;i<2048;i+=256) t2[i] = tw2[i];
    __syncthreads();
    float accs[32];
    #pragma unroll
    for (int m=0;m<32;++m) accs[m]=0.f;
    float bf = bil[g] + bhl[g];
    for (int d=0;d<64;++d){
        float w = Wil[g*128 + d];
        bf += w * tb2[d];
        #pragma unroll
        for (int m=0;m<32;++m) accs[m] += w * t2[d*32+m];
    }
    #pragma unroll
    for (int m=0;m<32;++m) Weff[g*32+m] = (_Float16)accs[m];
    biasL2[g] = bf;
}

__global__ void k_fcbpad(const float* __restrict__ fcb_in, float* __restrict__ fcb){
    int i = blockIdx.x*256 + threadIdx.x;
    if (i >= NPAD) return;
    fcb[i] = (i < VOC) ? fcb_in[i] : -1e30f;
}

// fc_out_w -> bf16 MFMA B-fragment layout: [tile][khalf][lane][8]
__global__ void k_fragb(const float* __restrict__ fcw, unsigned short* __restrict__ fragB){
    int idx = blockIdx.x*256 + threadIdx.x;   // 126*2*64 = 16128
    int lane = idx & 63, kh = (idx>>6)&1, tile = idx>>7;
    int n = tile*16 + (lane & 15);
    int k = kh*32 + (lane >> 4)*8;
    unsigned short* d = fragB + (size_t)((tile*2+kh)*64 + lane)*8;
    #pragma unroll
    for (int i=0;i<8;++i)
        d[i] = (n < VOC) ? bf16r(fcw[n*64 + k + i]) : (unsigned short)0;
}

// ---------------------------------------------------------------- recurrent kernel
// 2 batch rows per block, 512 threads (8 waves), BATCH/2 = 512 blocks,
// 2 blocks/CU (VGPR<=128 forced, LDS ~36KB).
// Thread (g = tid&255, hh = tid>>8) owns the k-half [hh*32, hh*32+32) of gate
// row g for all four h-consuming matrices (72 VGPRs of weights -> spill-free).
// Per step, 4 lgkm-only barriers:
//   P1 (all)    : att-gate half-partials + lang hl half-partial  -> B1
//   P2 (wave r) : att LSTM update, h-proj, scores, width-32
//                 shuffle softmax, trans1 (in-register)           -> B2
//   P3 (all)    : lang-gate half-partials (wEf u + wLHa ha)      -> B3
//   P4 (wave r) : lang LSTM update + h_hist store                 -> B4
__global__ __launch_bounds__(512, 4) void k_recur(
    const int* __restrict__ inst, const float* __restrict__ embW,
    const float* __restrict__ diff, const float* __restrict__ prev,
    const float* __restrict__ pre1, const float* __restrict__ pre2,
    const _Float16* __restrict__ attLp, const _Float16* __restrict__ attHp,
    const _Float16* __restrict__ wLhap, const _Float16* __restrict__ wLhlp,
    const _Float16* __restrict__ Weffp, const float* __restrict__ biasL2,
    const _Float16* __restrict__ w1fp,
    const float* __restrict__ a1w2, const float* __restrict__ a1b2,
    const float* __restrict__ a2w2, const float* __restrict__ a2b2,
    const float* __restrict__ tw1, const float* __restrict__ tb1,
    unsigned short* __restrict__ h_hist)
{
    const int tid  = threadIdx.x;           // 0..511
    const int g    = tid & 255;             // gate row
    const int hh   = tid >> 8;              // k-half
    const int wave = tid >> 6, lane = tid & 63;
    const int rb0  = blockIdx.x*2;          // rows rb0, rb0+1

    __shared__ float pbuf[2][2][256];                    // [half][row][gate]
    __shared__ __align__(16) _Float16 hl16[2][64];
    __shared__ __align__(16) _Float16 ha16[2][64];
    __shared__ __align__(16) _Float16 u16v[2][32];
    __shared__ __align__(16) float hpart[2][64];
    __shared__ __align__(16) float preS[2][2][25][36];   // stride 36: bank spread
    __shared__ __align__(16) float memS[2][200];
    __shared__ __align__(16) _Float16 w1fS[64*72];       // stride 72 f16
    __shared__ float tw1T[256];                          // transposed [8][32]
    __shared__ __align__(16) float w2S[2][32];
    __shared__ float b2S[2];
    __shared__ int   tokS[2][NSTEP];

    // ---- one-time block init (512-thread strides)
    for (int i=tid;i<2*NSTEP;i+=512){ int r=i/NSTEP, s=i-r*NSTEP; tokS[r][s]=inst[(rb0+r)*TT+s]; }
    for (int i=tid;i<3200;i+=512){
        int r = i/1600, rem = i - r*1600, h = rem/800, rem2 = rem - h*800, n = rem2>>5, k = rem2&31;
        preS[r][h][n][k] = (h ? pre2 : pre1)[(size_t)((rb0+r)*NOBJ+n)*32 + k];
    }
    for (int i=tid;i<400;i+=512){
        int r = i/200, rem = i - r*200;
        memS[r][rem] = (rem<100 ? diff : prev)[(size_t)(rb0+r)*100 + (rem%100)];
    }
    for (int i=tid;i<4096;i+=512){
        int rw = i>>6, k = i&63;
        w1fS[rw*72+k] = w1fp[i];
    }
    if (tid<256){ int m = tid&31, k = tid>>5; tw1T[k*32+m] = tw1[m*8+k]; }
    if (tid<64) w2S[tid>>5][tid&31] = (tid<32 ? a1w2 : a2w2)[tid&31];
    if (tid<2)  b2S[tid] = tid ? a2b2[0] : a1b2[0];
    if (tid<128){ hl16[tid>>6][tid&63]=(_Float16)0.f; ha16[tid>>6][tid&63]=(_Float16)0.f; }

    // ---- weight registers: half-row of each matrix (18 h8 = 72 VGPRs)
    h8 wAL[4], wAH[4], wLHa[4], wLHl[4], wEf[2];
    {
        const h8* p0 = (const h8*)(attLp + (size_t)g*64 + hh*32);
        const h8* p1 = (const h8*)(attHp + (size_t)g*64 + hh*32);
        const h8* p2 = (const h8*)(wLhap + (size_t)g*64 + hh*32);
        const h8* p3 = (const h8*)(wLhlp + (size_t)g*64 + hh*32);
        const h8* p4 = (const h8*)(Weffp + (size_t)g*32 + hh*16);
        #pragma unroll
        for (int k=0;k<4;++k){ wAL[k]=p0[k]; wAH[k]=p1[k]; wLHa[k]=p2[k]; wLHl[k]=p3[k]; }
        wEf[0]=p4[0]; wEf[1]=p4[1];
    }
    const float biasv = hh ? 0.f : biasL2[g];             // lang bias on half 0 only
    const float tb1v  = (lane < 32) ? tb1[lane] : 0.f;    // used by waves 0,1
    float c_att = 0.f, c_lang = 0.f;
    __syncthreads();

    // per-thread LDS half pointers (loop-invariant)
    const h8* xh0 = (const h8*)&hl16[0][hh*32];
    const h8* xh1 = (const h8*)&hl16[1][hh*32];
    const h8* xa0 = (const h8*)&ha16[0][hh*32];
    const h8* xa1 = (const h8*)&ha16[1][hh*32];
    const h8* xu0 = (const h8*)&u16v[0][hh*16];
    const h8* xu1 = (const h8*)&u16v[1][hh*16];

    // initial embW gather (half-0 threads carry the per-gate scalar)
    float ew0 = 0.f, ew1 = 0.f;
    if (hh == 0){
        ew0 = embW[(size_t)tokS[0][0]*256 + g];
        ew1 = embW[(size_t)tokS[1][0]*256 + g];
    }

    #pragma unroll 1
    for (int t=0;t<NSTEP;++t){
        // ---- P1: att-gate half-partials (both rows) + lang hl half-partial
        float a0 = hh ? 0.f : ew0;
        float a1 = hh ? 0.f : ew1;
        float p0 = biasv, p1 = biasv;
        if (hh == 0){   // prefetch next step's embW row (in flight across lgkm barriers)
            int tn = (t+1 < NSTEP) ? t+1 : NSTEP-1;
            ew0 = embW[(size_t)tokS[0][tn]*256 + g];
            ew1 = embW[(size_t)tokS[1][tn]*256 + g];
        }
        #pragma unroll
        for (int k=0;k<4;++k){
            h8 h0 = xh0[k], h1 = xh1[k];
            a0 = dot8(wAL[k],  h0, a0);  a1 = dot8(wAL[k],  h1, a1);
            p0 = dot8(wLHl[k], h0, p0);  p1 = dot8(wLHl[k], h1, p1);
        }
        #pragma unroll
        for (int k=0;k<4;++k){
            h8 v0 = xa0[k], v1 = xa1[k];
            a0 = dot8(wAH[k], v0, a0);   a1 = dot8(wAH[k], v1, a1);
        }
        pbuf[hh][0][g] = a0; pbuf[hh][1][g] = a1;
        block_sync_lds();                                    // B1

        // ---- P2: per-row serial section, wave r = row r (in-order DS per wave)
        if (wave < 2){
            const int r = wave;
            // att LSTM update (sum the two k-half partials)
            float gi = pbuf[0][r][lane]     + pbuf[1][r][lane];
            float gf = pbuf[0][r][64+lane]  + pbuf[1][r][64+lane];
            float gg = pbuf[0][r][128+lane] + pbuf[1][r][128+lane];
            float go = pbuf[0][r][192+lane] + pbuf[1][r][192+lane];
            float i_=sigf(gi), f_=sigf(gf), g_=tanh_(gg), o_=sigf(go);
            c_att = f_*c_att + i_*g_;
            ha16[r][lane] = (_Float16)(o_*tanh_(c_att));
            // h-projection: hp[lane] = w1f[lane] . ha
            {
                const h8* xa = (const h8*)&ha16[r][0];
                const h8* wr = (const h8*)&w1fS[lane*72];
                float hp = 0.f;
                #pragma unroll
                for (int k=0;k<8;++k) hp = dot8(wr[k], xa[k], hp);
                hpart[r][lane] = hp;
            }
            // scores: 2 heads x 25 objects (lane = half*32 + n)
            const int half = lane>>5, n = lane&31;
            float sc;
            {
                const float4* pp  = (const float4*)&preS[r][half][(n<NOBJ)?n:0][0];
                const float4* hp4 = (const float4*)&hpart[r][half*32];
                const float4* wv4 = (const float4*)&w2S[half][0];
                float a = b2S[half];
                #pragma unroll
                for (int i=0;i<8;++i){
                    float4 pv = pp[i], hv = hp4[i], wv = wv4[i];
                    a += fmaxf(hv.x+pv.x,0.f)*wv.x + fmaxf(hv.y+pv.y,0.f)*wv.y
                       + fmaxf(hv.z+pv.z,0.f)*wv.z + fmaxf(hv.w+pv.w,0.f)*wv.w;
                }
                sc = (n < NOBJ) ? a : -INFINITY;
            }
            // width-32 shuffle softmax + weighted memory sums (all lanes)
            float mx = sc;
            #pragma unroll
            for (int off=16; off; off>>=1) mx = fmaxf(mx, __shfl_xor(mx, off, 32));
            float e = __expf(sc - mx);                       // -inf -> 0
            float4 mm = {0.f,0.f,0.f,0.f};
            if (n < NOBJ) mm = ((const float4*)&memS[r][half*100])[n];
            float s = e, v0 = e*mm.x, v1 = e*mm.y, v2 = e*mm.z, v3 = e*mm.w;
            #pragma unroll
            for (int off=16; off; off>>=1){
                s  += __shfl_xor(s,  off, 32);
                v0 += __shfl_xor(v0, off, 32);
                v1 += __shfl_xor(v1, off, 32);
                v2 += __shfl_xor(v2, off, 32);
                v3 += __shfl_xor(v3, off, 32);
            }
            // pull head-1 sums into lanes<32, then trans stage 1 in-register
            float s1 = __shfl(s,  32|lane, 64);
            float w0 = __shfl(v0, 32|lane, 64);
            float w1 = __shfl(v1, 32|lane, 64);
            float w2 = __shfl(v2, 32|lane, 64);
            float w3 = __shfl(v3, 32|lane, 64);
            if (lane < 32){
                float inv0 = 1.f/s, inv1 = 1.f/s1;
                float u = tb1v
                    + (v0*inv0)*tw1T[0*32+lane] + (v1*inv0)*tw1T[1*32+lane]
                    + (v2*inv0)*tw1T[2*32+lane] + (v3*inv0)*tw1T[3*32+lane]
                    + (w0*inv1)*tw1T[4*32+lane] + (w1*inv1)*tw1T[5*32+lane]
                    + (w2*inv1)*tw1T[6*32+lane] + (w3*inv1)*tw1T[7*32+lane];
                u16v[r][lane] = (_Float16)fmaxf(u, 0.f);
            }
        }
        block_sync_lds();                                    // B2

        // ---- P3: lang-gate half-partials (wEf.u + wLHa.ha; wLHl.hl from P1)
        #pragma unroll
        for (int k=0;k<2;++k){
            p0 = dot8(wEf[k], xu0[k], p0);   p1 = dot8(wEf[k], xu1[k], p1);
        }
        #pragma unroll
        for (int k=0;k<4;++k){
            h8 v0 = xa0[k], v1 = xa1[k];
            p0 = dot8(wLHa[k], v0, p0);  p1 = dot8(wLHa[k], v1, p1);
        }
        pbuf[hh][0][g] = p0; pbuf[hh][1][g] = p1;
        block_sync_lds();                                    // B3

        // ---- P4: lang LSTM update + h_hist store (wave r = row r)
        if (wave < 2){
            const int r = wave;
            float gi = pbuf[0][r][lane]     + pbuf[1][r][lane];
            float gf = pbuf[0][r][64+lane]  + pbuf[1][r][64+lane];
            float gg = pbuf[0][r][128+lane] + pbuf[1][r][128+lane];
            float go = pbuf[0][r][192+lane] + pbuf[1][r][192+lane];
            float i_=sigf(gi), f_=sigf(gf), g_=tanh_(gg), o_=sigf(go);
            c_lang = f_*c_lang + i_*g_;
            float hL = o_*tanh_(c_lang);
            hl16[r][lane] = (_Float16)hL;
            h_hist[((size_t)(rb0+r)*NSTEP + t)*64 + lane] = bf16r(hL);
        }
        block_sync_lds();                                    // B4
    }
}

// ---------------------------------------------------------------- fc + log_softmax

__global__ __launch_bounds__(256) void k_fc(const unsigned short* __restrict__ h_hist,
                                            const unsigned short* __restrict__ fragB,
                                            const float* __restrict__ fcb,
                                            float* __restrict__ out)
{
    const int tid = threadIdx.x;
    const int w = tid >> 6, lane = tid & 63;
    const int q = lane >> 4, l16 = lane & 15;
    const int rowbase = blockIdx.x*16;

    const short8 a0 = *(const short8*)(h_hist + (size_t)(rowbase + l16)*64 + q*8);
    const short8 a1 = *(const short8*)(h_hist + (size_t)(rowbase + l16)*64 + 32 + q*8);

    float m[4], s[4];
    #pragma unroll
    for (int i=0;i<4;++i){ m[i] = -INFINITY; s[i] = 0.f; }

    for (int tile = w; tile < NTILE; tile += 4){
        const short8 b0 = *(const short8*)(fragB + (size_t)((tile*2+0)*64 + lane)*8);
        const short8 b1 = *(const short8*)(fragB + (size_t)((tile*2+1)*64 + lane)*8);
        f32x4 acc = {0.f,0.f,0.f,0.f};
        acc = __builtin_amdgcn_mfma_f32_16x16x32_bf16(a0, b0, acc, 0, 0, 0);
        acc = __builtin_amdgcn_mfma_f32_16x16x32_bf16(a1, b1, acc, 0, 0, 0);
        float bias = fcb[tile*16 + l16];
        #pragma unroll
        for (int i=0;i<4;++i){
            float v = acc[i] + bias;
            float nm = fmaxf(m[i], v);
            s[i] = s[i]*__expf(m[i]-nm) + __expf(v-nm);
            m[i] = nm;
        }
    }
    #pragma unroll
    for (int i=0;i<4;++i){
        #pragma unroll
        for (int off=1; off<16; off<<=1){
            float om = __shfl_xor(m[i], off, 64);
            float os = __shfl_xor(s[i], off, 64);
            float nm = fmaxf(m[i], om);
            s[i] = s[i]*__expf(m[i]-nm) + os*__expf(om-nm);
            m[i] = nm;
        }
    }
    __shared__ float lm[4][16], ls[4][16], fm[16], fl[16];
    if (l16 == 0){
        #pragma unroll
        for (int i=0;i<4;++i){ lm[w][q*4+i] = m[i]; ls[w][q*4+i] = s[i]; }
    }
    __syncthreads();
    if (tid < 16){
        float M = -INFINITY, S = 0.f;
        #pragma unroll
        for (int ww=0;ww<4;++ww){
            float om = lm[ww][tid], os = ls[ww][tid];
            float nm = fmaxf(M, om);
            S = S*__expf(M-nm) + os*__expf(om-nm);
            M = nm;
        }
        fm[tid] = M; fl[tid] = __logf(S);
    }
    __syncthreads();
    float Mr[4], Lr[4];
    #pragma unroll
    for (int i=0;i<4;++i){ Mr[i] = fm[q*4+i]; Lr[i] = fl[q*4+i]; }

    for (int tile = w; tile < NTILE; tile += 4){
        const short8 b0 = *(const short8*)(fragB + (size_t)((tile*2+0)*64 + lane)*8);
        const short8 b1 = *(const short8*)(fragB + (size_t)((tile*2+1)*64 + lane)*8);
        f32x4 acc = {0.f,0.f,0.f,0.f};
        acc = __builtin_amdgcn_mfma_f32_16x16x32_bf16(a0, b0, acc, 0, 0, 0);
        acc = __builtin_amdgcn_mfma_f32_16x16x32_bf16(a1, b1, acc, 0, 0, 0);
        int col = tile*16 + l16;
        if (col < VOC){
            float bias = fcb[col];
            #pragma unroll
            for (int i=0;i<4;++i)
                out[(size_t)(rowbase + q*4 + i)*VOC + col] = acc[i] + bias - Mr[i] - Lr[i];
        }
    }
}

// ---------------------------------------------------------------- launcher

extern "C" void kernel_launch(void* const* d_in, const int* in_sizes, int n_in,
                              void* d_out, int out_size, void* d_ws, size_t ws_size,
                              hipStream_t stream)
{
    const int*   inst  = (const int*)  d_in[0];
    const float* prev  = (const float*)d_in[1];
    const float* fin   = (const float*)d_in[2];
    const float* embed = (const float*)d_in[3];
    const float* Wia   = (const float*)d_in[4];
    const float* Wha   = (const float*)d_in[5];
    const float* bia   = (const float*)d_in[6];
    const float* bha   = (const float*)d_in[7];
    const float* Wil   = (const float*)d_in[8];
    const float* Whl   = (const float*)d_in[9];
    const float* bil   = (const float*)d_in[10];
    const float* bhl   = (const float*)d_in[11];
    const float* fcw   = (const float*)d_in[12];
    const float* fcbi  = (const float*)d_in[13];
    const float* a1w1  = (const float*)d_in[14];
    const float* a1b1  = (const float*)d_in[15];
    const float* a1w2  = (const float*)d_in[16];
    const float* a1b2  = (const float*)d_in[17];
    const float* a2w1  = (const float*)d_in[18];
    const float* a2b1  = (const float*)d_in[19];
    const float* a2w2  = (const float*)d_in[20];
    const float* a2b2  = (const float*)d_in[21];
    const float* tw1   = (const float*)d_in[22];
    const float* tb1   = (const float*)d_in[23];
    const float* tw2   = (const float*)d_in[24];
    const float* tb2   = (const float*)d_in[25];
    float* out = (float*)d_out;

    char* wsb = (char*)d_ws; size_t off = 0;
    auto alloc = [&](size_t bytes)->char*{
        char* p = wsb + off; off = (off + bytes + 511) & ~(size_t)511; return p;
    };
    float*          embW  = (float*)alloc((size_t)VOC*256*4);
    float*          diff  = (float*)alloc((size_t)BATCH*NOBJ*4*4);
    float*          pre1  = (float*)alloc((size_t)BATCH*NOBJ*32*4);
    float*          pre2  = (float*)alloc((size_t)BATCH*NOBJ*32*4);
    _Float16*       attLp = (_Float16*)alloc((size_t)256*64*2);
    _Float16*       attHp = (_Float16*)alloc((size_t)256*64*2);
    _Float16*       wLhap = (_Float16*)alloc((size_t)256*64*2);
    _Float16*       wLhlp = (_Float16*)alloc((size_t)256*64*2);
    _Float16*       Weffp = (_Float16*)alloc((size_t)256*32*2);
    _Float16*       w1fp  = (_Float16*)alloc((size_t)64*64*2);
    float*          biasL2= (float*)alloc(256*4);
    float*          fcb   = (float*)alloc((size_t)NPAD*4);
    unsigned short* hhist = (unsigned short*)alloc((size_t)NROWS*64*2);
    unsigned short* fragB = (unsigned short*)alloc((size_t)NTILE*2*64*8*2);

    // prep
    k_pre    <<<(BATCH*NOBJ+255)/256, 256, 0, stream>>>(prev, fin, a1w1, a1b1, a2w1, a2b1, diff, pre1, pre2);
    k_embw   <<<VOC, 256, 0, stream>>>(embed, Wia, bia, bha, embW);
    k_packrow<<<64, 256, 0, stream>>>(Wia, attLp, 128, 0,  64, 256*64);   // W_ih_att[:, :64]  (h_lang)
    k_packrow<<<64, 256, 0, stream>>>(Wha, attHp,  64, 0,  64, 256*64);   // W_hh_att          (h_att)
    k_packrow<<<64, 256, 0, stream>>>(Wil, wLhap, 128, 64, 64, 256*64);   // W_ih_lang[:,64:]  (h_att)
    k_packrow<<<64, 256, 0, stream>>>(Whl, wLhlp,  64, 0,  64, 256*64);   // W_hh_lang         (h_lang)
    k_packrow<<<8,  256, 0, stream>>>(a1w1, w1fp,       68, 0, 64, 32*64);// att1 w1[:, :64]
    k_packrow<<<8,  256, 0, stream>>>(a2w1, w1fp+32*64, 68, 0, 64, 32*64);// att2 w1[:, :64]
    k_weff   <<<1, 256, 0, stream>>>(Wil, tw2, tb2, bil, bhl, Weffp, biasL2);
    k_fcbpad <<<(NPAD+255)/256, 256, 0, stream>>>(fcbi, fcb);
    k_fragb  <<<63, 256, 0, stream>>>(fcw, fragB);

    // recurrent scan: 2 batch rows per block, k-half-split threads
    k_recur<<<BATCH/2, 512, 0, stream>>>(inst, embW, diff, prev, pre1, pre2,
                                         attLp, attHp, wLhap, wLhlp, Weffp, biasL2, w1fp,
                                         a1w2, a1b2, a2w2, a2b2, tw1, tb1, hhist);

    // big projection + log_softmax
    k_fc<<<NROWS/16, 256, 0, stream>>>(hhist, fragB, fcb, out);
}

// Round 3
// 809.996 us; speedup vs baseline: 1.3422x; 1.3422x over previous
//
#include <hip/hip_runtime.h>

// Problem constants
#define BATCH 1024
#define TT 48          // inst columns
#define NSTEP 47       // scan steps
#define VOC 2001       // V+1
#define RNN 64
#define NOBJ 25
#define NROWS (BATCH*NSTEP)   // 48128
#define NTILE 126             // ceil(2016/16)
#define NPAD 2016

typedef _Float16 h2 __attribute__((ext_vector_type(2)));
typedef _Float16 h8 __attribute__((ext_vector_type(8)));
typedef short short8 __attribute__((ext_vector_type(8)));
typedef float f32x4 __attribute__((ext_vector_type(4)));

__device__ __forceinline__ float fdot2f(h2 a, h2 b, float c){
#if __has_builtin(__builtin_amdgcn_fdot2)
    return __builtin_amdgcn_fdot2(a, b, c, false);
#else
    return c + (float)a[0]*(float)b[0] + (float)a[1]*(float)b[1];
#endif
}

__device__ __forceinline__ float dot8(h8 w, h8 x, float acc){
    acc = fdot2f(__builtin_shufflevector(w,w,0,1), __builtin_shufflevector(x,x,0,1), acc);
    acc = fdot2f(__builtin_shufflevector(w,w,2,3), __builtin_shufflevector(x,x,2,3), acc);
    acc = fdot2f(__builtin_shufflevector(w,w,4,5), __builtin_shufflevector(x,x,4,5), acc);
    acc = fdot2f(__builtin_shufflevector(w,w,6,7), __builtin_shufflevector(x,x,6,7), acc);
    return acc;
}

__device__ __forceinline__ float sigf(float x){ return 1.f/(1.f+__expf(-x)); }
__device__ __forceinline__ float tanh_(float x){
    float e = __expf(2.f*fminf(x, 15.f));   // clamp avoids inf/inf NaN
    return (e-1.f)/(e+1.f);
}
__device__ __forceinline__ unsigned short bf16r(float f){
    unsigned u = __float_as_uint(f);
    return (unsigned short)((u + 0x7FFFu + ((u>>16)&1u)) >> 16);
}

// LDS-only barrier: publishes ds_writes (lgkmcnt) but does NOT drain vmcnt,
// so embW prefetch / h_hist stores pipeline across it. No cross-thread
// communication through global memory happens inside the recurrent loop.
__device__ __forceinline__ void block_sync_lds(){
    asm volatile("s_waitcnt lgkmcnt(0)" ::: "memory");
    __builtin_amdgcn_s_barrier();
    asm volatile("" ::: "memory");
}

// byte offset of 16B chunk `cb` (byte units) in a 128B row, XOR-swizzled
#define SWZ(row, cb) (((row)<<7) + ((cb) ^ (((row)&7)<<4)))

// ---------------------------------------------------------------- prep kernels

// diff_canvas + time-invariant attention terms pre1/pre2 [B,25,32]
__global__ void k_pre(const float* __restrict__ prev, const float* __restrict__ fin,
                      const float* __restrict__ a1w1, const float* __restrict__ a1b1,
                      const float* __restrict__ a2w1, const float* __restrict__ a2b1,
                      float* __restrict__ diff, float* __restrict__ pre1, float* __restrict__ pre2){
    int idx = blockIdx.x*256 + threadIdx.x;
    if (idx >= BATCH*NOBJ) return;
    float p0 = prev[idx*4+0], p1 = prev[idx*4+1], p2 = prev[idx*4+2], p3 = prev[idx*4+3];
    bool masked = (p0+p1+p2+p3) > 0.f;
    float d0 = masked ? -1.f : fin[idx*4+0];
    float d1 = masked ? -1.f : fin[idx*4+1];
    float d2 = masked ? -1.f : fin[idx*4+2];
    float d3 = masked ? -1.f : fin[idx*4+3];
    diff[idx*4+0]=d0; diff[idx*4+1]=d1; diff[idx*4+2]=d2; diff[idx*4+3]=d3;
    for (int j=0;j<32;++j){
        const float* w1 = a1w1 + j*68 + 64;
        const float* w2 = a2w1 + j*68 + 64;
        pre1[idx*32+j] = a1b1[j] + d0*w1[0] + d1*w1[1] + d2*w1[2] + d3*w1[3];
        pre2[idx*32+j] = a2b1[j] + p0*w2[0] + p1*w2[1] + p2*w2[2] + p3*w2[3];
    }
}

// embW[v][g] = b_ih_att[g]+b_hh_att[g] + sum_k embed[v][k]*W_ih_att[g][64+k]
__global__ void k_embw(const float* __restrict__ embed, const float* __restrict__ Wia,
                       const float* __restrict__ bia, const float* __restrict__ bha,
                       float* __restrict__ embW){
    int v = blockIdx.x, g = threadIdx.x;
    __shared__ float er[64];
    if (g < 64) er[g] = embed[v*64+g];
    __syncthreads();
    float acc = bia[g] + bha[g];
    const float* wr = Wia + g*128 + 64;
    #pragma unroll 8
    for (int k=0;k<64;++k) acc += er[k]*wr[k];
    embW[v*256+g] = acc;
}

// pack fp32 weight rows [G][srcK] cols koff..koff+K-1 -> f16 row-major [G][K]
__global__ void k_packrow(const float* __restrict__ src, _Float16* __restrict__ dst,
                          int srcK, int koff, int K, int total){
    int idx = blockIdx.x*256 + threadIdx.x;
    if (idx >= total) return;
    int k = idx % K, g = idx / K;
    dst[idx] = (_Float16)src[g*srcK + koff + k];
}

// Weff[g][m] = sum_d W_ih_lang[g][d]*tw2[d][m]; biasL2[g] = bil+bhl+sum_d W[g][d]*tb2[d]
__global__ void k_weff(const float* __restrict__ Wil, const float* __restrict__ tw2,
                       const float* __restrict__ tb2, const float* __restrict__ bil,
                       const float* __restrict__ bhl, _Float16* __restrict__ Weff,
                       float* __restrict__ biasL2){
    __shared__ float t2[64*32];
    int g = threadIdx.x;
    for (int i=g;i<2048;i+=256) t2[i] = tw2[i];
    __syncthreads();
    float accs[32];
    #pragma unroll
    for (int m=0;m<32;++m) accs[m]=0.f;
    float bf = bil[g] + bhl[g];
    for (int d=0;d<64;++d){
        float w = Wil[g*128 + d];
        bf += w * tb2[d];
        #pragma unroll
        for (int m=0;m<32;++m) accs[m] += w * t2[d*32+m];
    }
    #pragma unroll
    for (int m=0;m<32;++m) Weff[g*32+m] = (_Float16)accs[m];
    biasL2[g] = bf;
}

__global__ void k_fcbpad(const float* __restrict__ fcb_in, float* __restrict__ fcb){
    int i = blockIdx.x*256 + threadIdx.x;
    if (i >= NPAD) return;
    fcb[i] = (i < VOC) ? fcb_in[i] : -1e30f;
}

// fc_out_w -> bf16 MFMA B-fragment layout: [tile][khalf][lane][8]
__global__ void k_fragb(const float* __restrict__ fcw, unsigned short* __restrict__ fragB){
    int idx = blockIdx.x*256 + threadIdx.x;   // 126*2*64 = 16128
    int lane = idx & 63, kh = (idx>>6)&1, tile = idx>>7;
    int n = tile*16 + (lane & 15);
    int k = kh*32 + (lane >> 4)*8;
    unsigned short* d = fragB + (size_t)((tile*2+kh)*64 + lane)*8;
    #pragma unroll
    for (int i=0;i<8;++i)
        d[i] = (n < VOC) ? bf16r(fcw[n*64 + k + i]) : (unsigned short)0;
}

// ---------------------------------------------------------------- recurrent kernel
// 4 batch rows per block, 1024 threads (16 waves), 256 blocks = 1 block/CU.
// Thread (g = tid&255, qq = tid>>8) owns the k-QUARTER [qq*16, qq*16+16) of
// gate row g of all weight matrices: 9 h8 = 36 VGPRs, loaded ONCE from L2 at
// init and resident forever (no per-step weight streaming — the round-0/1
// L2 bottleneck). LDS is padded >80KB so only 1 block/CU fits, which pins the
// allocator's occupancy target to 4 waves/EU -> VGPR budget 128 >> demand
// (~90) -> no spill (the round-2 failure). amdgpu_waves_per_eu(4,4) is the
// second line of defense.
// Per step, 4 lgkm-only barriers:
//   P1 (all)     : att-gate quarter-partials (4 rows) + lang hl partial -> B1
//   P2 (wave r<4): att LSTM update, h-proj, scores, width-32 shuffle
//                  softmax, trans1 for row r (in-order DS per wave)     -> B2
//   P3 (all)     : lang-gate quarter-partials (wEf u + wLHa ha)         -> B3
//   P4 (wave r<4): lang LSTM update + h_hist store                      -> B4
__global__ __attribute__((amdgpu_waves_per_eu(4,4))) __launch_bounds__(1024)
void k_recur(
    const int* __restrict__ inst, const float* __restrict__ embW,
    const float* __restrict__ diff, const float* __restrict__ prev,
    const float* __restrict__ pre1, const float* __restrict__ pre2,
    const _Float16* __restrict__ attLp, const _Float16* __restrict__ attHp,
    const _Float16* __restrict__ wLhap, const _Float16* __restrict__ wLhlp,
    const _Float16* __restrict__ Weffp, const float* __restrict__ biasL2,
    const _Float16* __restrict__ w1fp,
    const float* __restrict__ a1w2, const float* __restrict__ a1b2,
    const float* __restrict__ a2w2, const float* __restrict__ a2b2,
    const float* __restrict__ tw1, const float* __restrict__ tb1,
    unsigned short* __restrict__ h_hist)
{
    const int tid  = threadIdx.x;           // 0..1023
    const int g    = tid & 255;             // gate row
    const int qq   = tid >> 8;              // k-quarter 0..3
    const int wave = tid >> 6, lane = tid & 63;
    const int rb0  = blockIdx.x*4;          // rows rb0..rb0+3

    __shared__ float pbuf[4][4][256];                    // [quarter][row][gate]
    __shared__ __align__(16) float preS[4][2][25][36];   // stride 36: 16B-aligned float4
    __shared__ __align__(16) _Float16 hl16[4][64];
    __shared__ __align__(16) _Float16 ha16[4][64];
    __shared__ __align__(16) _Float16 u16v[4][32];
    __shared__ __align__(16) float hpart[4][64];
    __shared__ __align__(16) float memS[4][200];
    __shared__ __align__(16) char w1fb[64*128];          // swizzled h-proj weights
    __shared__ float tw1T[256];                          // transposed [8][32]
    __shared__ __align__(16) float w2S[2][32];
    __shared__ float b2S[2];
    __shared__ int   tokS[4][NSTEP];
    // pad LDS above 80KB: 2 blocks/CU impossible -> occupancy pinned at
    // 16 waves/CU = 4 waves/EU -> VGPR budget 128 (anti-spill; see header)
    __shared__ float lds_pad[5600];
    if (tid == 0) ((volatile float*)lds_pad)[0] = 0.f;

    // ---- one-time block init (1024-thread strides)
    for (int i=tid;i<4*NSTEP;i+=1024){ int r=i/NSTEP, s=i-r*NSTEP; tokS[r][s]=inst[(rb0+r)*TT+s]; }
    for (int i=tid;i<6400;i+=1024){
        int r = i/1600, rem = i - r*1600, h = rem/800, rem2 = rem - h*800, n = rem2>>5, k = rem2&31;
        preS[r][h][n][k] = (h ? pre2 : pre1)[(size_t)((rb0+r)*NOBJ+n)*32 + k];
    }
    for (int i=tid;i<800;i+=1024){
        int r = i/200, rem = i - r*200;
        memS[r][rem] = (rem<100 ? diff : prev)[(size_t)(rb0+r)*100 + (rem%100)];
    }
    for (int i=tid;i<512;i+=1024){           // w1f: 64 rows x 8 chunks, swizzled
        int row = i>>3, ch = i&7;
        *(h8*)(w1fb + SWZ(row, ch*16)) = *(const h8*)(w1fp + (size_t)row*64 + ch*8);
    }
    if (tid<256){ int m = tid&31, k = tid>>5; tw1T[k*32+m] = tw1[m*8+k]; }
    if (tid<64) w2S[tid>>5][tid&31] = (tid<32 ? a1w2 : a2w2)[tid&31];
    if (tid<2)  b2S[tid] = tid ? a2b2[0] : a1b2[0];
    if (tid<256){ hl16[tid>>6][tid&63]=(_Float16)0.f; ha16[tid>>6][tid&63]=(_Float16)0.f; }

    // ---- resident weight registers: quarter-row of each matrix (9 h8 = 36 VGPR)
    h8 wA0, wA1, wH0, wH1, wLl0, wLl1, wLa0, wLa1, wEfv;
    {
        const h8* pA = (const h8*)(attLp + (size_t)g*64 + qq*16);
        const h8* pH = (const h8*)(attHp + (size_t)g*64 + qq*16);
        const h8* pL = (const h8*)(wLhlp + (size_t)g*64 + qq*16);
        const h8* pa = (const h8*)(wLhap + (size_t)g*64 + qq*16);
        wA0 = pA[0]; wA1 = pA[1];
        wH0 = pH[0]; wH1 = pH[1];
        wLl0 = pL[0]; wLl1 = pL[1];
        wLa0 = pa[0]; wLa1 = pa[1];
        wEfv = *(const h8*)(Weffp + (size_t)g*32 + qq*8);
    }
    const float biasv = (qq==0) ? biasL2[g] : 0.f;
    const float tb1v  = (wave<4 && lane<32) ? tb1[lane] : 0.f;
    float c_att = 0.f, c_lang = 0.f;
    __syncthreads();

    // initial embW gather (quarter-0 threads carry the per-gate scalar)
    float ew[4] = {0.f,0.f,0.f,0.f};
    if (qq == 0){
        #pragma unroll
        for (int r=0;r<4;++r) ew[r] = embW[(size_t)tokS[r][0]*256 + g];
    }

    #pragma unroll 1
    for (int t=0;t<NSTEP;++t){
        // ---- P1: att-gate quarter-partials (4 rows) + lang hl partials
        float p[4];
        #pragma unroll
        for (int r=0;r<4;++r) p[r] = biasv;
        #pragma unroll
        for (int r=0;r<4;++r){
            h8 x0 = ((const h8*)&hl16[r][0])[qq*2];
            h8 x1 = ((const h8*)&hl16[r][0])[qq*2+1];
            h8 y0 = ((const h8*)&ha16[r][0])[qq*2];
            h8 y1 = ((const h8*)&ha16[r][0])[qq*2+1];
            float a = (qq==0) ? ew[r] : 0.f;
            a = dot8(wA0, x0, a); a = dot8(wA1, x1, a);
            a = dot8(wH0, y0, a); a = dot8(wH1, y1, a);
            pbuf[qq][r][g] = a;
            p[r] = dot8(wLl0, x0, p[r]);
            p[r] = dot8(wLl1, x1, p[r]);
        }
        if (qq == 0){   // prefetch next step's embW (stays in flight across lgkm barriers)
            int tn = (t+1 < NSTEP) ? t+1 : NSTEP-1;
            #pragma unroll
            for (int r=0;r<4;++r) ew[r] = embW[(size_t)tokS[r][tn]*256 + g];
        }
        block_sync_lds();                                    // B1

        // ---- P2: per-row serial section, wave r = row r (in-order DS per wave)
        if (wave < 4){
            const int r = wave;
            const int half = lane>>5, n = lane&31;
            // att LSTM update (sum 4 quarter-partials)
            float gi = (pbuf[0][r][lane]     + pbuf[1][r][lane])     + (pbuf[2][r][lane]     + pbuf[3][r][lane]);
            float gf = (pbuf[0][r][64+lane]  + pbuf[1][r][64+lane])  + (pbuf[2][r][64+lane]  + pbuf[3][r][64+lane]);
            float gg = (pbuf[0][r][128+lane] + pbuf[1][r][128+lane]) + (pbuf[2][r][128+lane] + pbuf[3][r][128+lane]);
            float go = (pbuf[0][r][192+lane] + pbuf[1][r][192+lane]) + (pbuf[2][r][192+lane] + pbuf[3][r][192+lane]);
            float i_=sigf(gi), f_=sigf(gf), g_=tanh_(gg), o_=sigf(go);
            c_att = f_*c_att + i_*g_;
            ha16[r][lane] = (_Float16)(o_*tanh_(c_att));
            // h-projection: hp[lane] = w1f[lane] . ha  (swizzled LDS reads)
            {
                const h8* xa = (const h8*)&ha16[r][0];
                float hp = 0.f;
                #pragma unroll
                for (int k=0;k<8;++k)
                    hp = dot8(*(const h8*)(w1fb + SWZ(lane, k*16)), xa[k], hp);
                hpart[r][lane] = hp;
            }
            // scores: 2 heads x 25 objects (lane = half*32 + n)
            float sc;
            {
                const float4* pp  = (const float4*)&preS[r][half][(n<NOBJ)?n:0][0];
                const float4* hp4 = (const float4*)&hpart[r][half*32];
                const float4* wv4 = (const float4*)&w2S[half][0];
                float a = b2S[half];
                #pragma unroll
                for (int i=0;i<8;++i){
                    float4 pv = pp[i], hv = hp4[i], wv = wv4[i];
                    a += fmaxf(hv.x+pv.x,0.f)*wv.x + fmaxf(hv.y+pv.y,0.f)*wv.y
                       + fmaxf(hv.z+pv.z,0.f)*wv.z + fmaxf(hv.w+pv.w,0.f)*wv.w;
                }
                sc = (n < NOBJ) ? a : -INFINITY;
            }
            // width-32 shuffle softmax + weighted memory sums
            float mx = sc;
            #pragma unroll
            for (int off=16; off; off>>=1) mx = fmaxf(mx, __shfl_xor(mx, off, 32));
            float e = __expf(sc - mx);                       // -inf -> 0
            float4 mm = {0.f,0.f,0.f,0.f};
            if (n < NOBJ) mm = ((const float4*)&memS[r][half*100])[n];
            float s = e, v0 = e*mm.x, v1 = e*mm.y, v2 = e*mm.z, v3 = e*mm.w;
            #pragma unroll
            for (int off=16; off; off>>=1){
                s  += __shfl_xor(s,  off, 32);
                v0 += __shfl_xor(v0, off, 32);
                v1 += __shfl_xor(v1, off, 32);
                v2 += __shfl_xor(v2, off, 32);
                v3 += __shfl_xor(v3, off, 32);
            }
            // pull head-1 sums into lanes<32, then trans stage 1 in-register
            float s1 = __shfl(s,  32|lane, 64);
            float w0 = __shfl(v0, 32|lane, 64);
            float w1 = __shfl(v1, 32|lane, 64);
            float w2 = __shfl(v2, 32|lane, 64);
            float w3 = __shfl(v3, 32|lane, 64);
            if (lane < 32){
                float inv0 = 1.f/s, inv1 = 1.f/s1;
                float u = tb1v
                    + (v0*inv0)*tw1T[0*32+lane] + (v1*inv0)*tw1T[1*32+lane]
                    + (v2*inv0)*tw1T[2*32+lane] + (v3*inv0)*tw1T[3*32+lane]
                    + (w0*inv1)*tw1T[4*32+lane] + (w1*inv1)*tw1T[5*32+lane]
                    + (w2*inv1)*tw1T[6*32+lane] + (w3*inv1)*tw1T[7*32+lane];
                u16v[r][lane] = (_Float16)fmaxf(u, 0.f);
            }
        }
        block_sync_lds();                                    // B2

        // ---- P3: lang-gate quarter-partials (wEf.u + wLHa.ha; wLHl.hl from P1)
        #pragma unroll
        for (int r=0;r<4;++r){
            h8 u  = ((const h8*)&u16v[r][0])[qq];
            h8 y0 = ((const h8*)&ha16[r][0])[qq*2];
            h8 y1 = ((const h8*)&ha16[r][0])[qq*2+1];
            float pv = p[r];
            pv = dot8(wEfv, u, pv);
            pv = dot8(wLa0, y0, pv);
            pv = dot8(wLa1, y1, pv);
            pbuf[qq][r][g] = pv;
        }
        block_sync_lds();                                    // B3

        // ---- P4: lang LSTM update + h_hist store (wave r = row r)
        if (wave < 4){
            const int r = wave;
            float gi = (pbuf[0][r][lane]     + pbuf[1][r][lane])     + (pbuf[2][r][lane]     + pbuf[3][r][lane]);
            float gf = (pbuf[0][r][64+lane]  + pbuf[1][r][64+lane])  + (pbuf[2][r][64+lane]  + pbuf[3][r][64+lane]);
            float gg = (pbuf[0][r][128+lane] + pbuf[1][r][128+lane]) + (pbuf[2][r][128+lane] + pbuf[3][r][128+lane]);
            float go = (pbuf[0][r][192+lane] + pbuf[1][r][192+lane]) + (pbuf[2][r][192+lane] + pbuf[3][r][192+lane]);
            float i_=sigf(gi), f_=sigf(gf), g_=tanh_(gg), o_=sigf(go);
            c_lang = f_*c_lang + i_*g_;
            float hL = o_*tanh_(c_lang);
            hl16[r][lane] = (_Float16)hL;
            h_hist[((size_t)(rb0+r)*NSTEP + t)*64 + lane] = bf16r(hL);
        }
        block_sync_lds();                                    // B4
    }
}

// ---------------------------------------------------------------- fc + log_softmax

__global__ __launch_bounds__(256) void k_fc(const unsigned short* __restrict__ h_hist,
                                            const unsigned short* __restrict__ fragB,
                                            const float* __restrict__ fcb,
                                            float* __restrict__ out)
{
    const int tid = threadIdx.x;
    const int w = tid >> 6, lane = tid & 63;
    const int q = lane >> 4, l16 = lane & 15;
    const int rowbase = blockIdx.x*16;

    const short8 a0 = *(const short8*)(h_hist + (size_t)(rowbase + l16)*64 + q*8);
    const short8 a1 = *(const short8*)(h_hist + (size_t)(rowbase + l16)*64 + 32 + q*8);

    float m[4], s[4];
    #pragma unroll
    for (int i=0;i<4;++i){ m[i] = -INFINITY; s[i] = 0.f; }

    for (int tile = w; tile < NTILE; tile += 4){
        const short8 b0 = *(const short8*)(fragB + (size_t)((tile*2+0)*64 + lane)*8);
        const short8 b1 = *(const short8*)(fragB + (size_t)((tile*2+1)*64 + lane)*8);
        f32x4 acc = {0.f,0.f,0.f,0.f};
        acc = __builtin_amdgcn_mfma_f32_16x16x32_bf16(a0, b0, acc, 0, 0, 0);
        acc = __builtin_amdgcn_mfma_f32_16x16x32_bf16(a1, b1, acc, 0, 0, 0);
        float bias = fcb[tile*16 + l16];
        #pragma unroll
        for (int i=0;i<4;++i){
            float v = acc[i] + bias;
            float nm = fmaxf(m[i], v);
            s[i] = s[i]*__expf(m[i]-nm) + __expf(v-nm);
            m[i] = nm;
        }
    }
    #pragma unroll
    for (int i=0;i<4;++i){
        #pragma unroll
        for (int off=1; off<16; off<<=1){
            float om = __shfl_xor(m[i], off, 64);
            float os = __shfl_xor(s[i], off, 64);
            float nm = fmaxf(m[i], om);
            s[i] = s[i]*__expf(m[i]-nm) + os*__expf(om-nm);
            m[i] = nm;
        }
    }
    __shared__ float lm[4][16], ls[4][16], fm[16], fl[16];
    if (l16 == 0){
        #pragma unroll
        for (int i=0;i<4;++i){ lm[w][q*4+i] = m[i]; ls[w][q*4+i] = s[i]; }
    }
    __syncthreads();
    if (tid < 16){
        float M = -INFINITY, S = 0.f;
        #pragma unroll
        for (int ww=0;ww<4;++ww){
            float om = lm[ww][tid], os = ls[ww][tid];
            float nm = fmaxf(M, om);
            S = S*__expf(M-nm) + os*__expf(om-nm);
            M = nm;
        }
        fm[tid] = M; fl[tid] = __logf(S);
    }
    __syncthreads();
    float Mr[4], Lr[4];
    #pragma unroll
    for (int i=0;i<4;++i){ Mr[i] = fm[q*4+i]; Lr[i] = fl[q*4+i]; }

    for (int tile = w; tile < NTILE; tile += 4){
        const short8 b0 = *(const short8*)(fragB + (size_t)((tile*2+0)*64 + lane)*8);
        const short8 b1 = *(const short8*)(fragB + (size_t)((tile*2+1)*64 + lane)*8);
        f32x4 acc = {0.f,0.f,0.f,0.f};
        acc = __builtin_amdgcn_mfma_f32_16x16x32_bf16(a0, b0, acc, 0, 0, 0);
        acc = __builtin_amdgcn_mfma_f32_16x16x32_bf16(a1, b1, acc, 0, 0, 0);
        int col = tile*16 + l16;
        if (col < VOC){
            float bias = fcb[col];
            #pragma unroll
            for (int i=0;i<4;++i)
                out[(size_t)(rowbase + q*4 + i)*VOC + col] = acc[i] + bias - Mr[i] - Lr[i];
        }
    }
}

// ---------------------------------------------------------------- launcher

extern "C" void kernel_launch(void* const* d_in, const int* in_sizes, int n_in,
                              void* d_out, int out_size, void* d_ws, size_t ws_size,
                              hipStream_t stream)
{
    const int*   inst  = (const int*)  d_in[0];
    const float* prev  = (const float*)d_in[1];
    const float* fin   = (const float*)d_in[2];
    const float* embed = (const float*)d_in[3];
    const float* Wia   = (const float*)d_in[4];
    const float* Wha   = (const float*)d_in[5];
    const float* bia   = (const float*)d_in[6];
    const float* bha   = (const float*)d_in[7];
    const float* Wil   = (const float*)d_in[8];
    const float* Whl   = (const float*)d_in[9];
    const float* bil   = (const float*)d_in[10];
    const float* bhl   = (const float*)d_in[11];
    const float* fcw   = (const float*)d_in[12];
    const float* fcbi  = (const float*)d_in[13];
    const float* a1w1  = (const float*)d_in[14];
    const float* a1b1  = (const float*)d_in[15];
    const float* a1w2  = (const float*)d_in[16];
    const float* a1b2  = (const float*)d_in[17];
    const float* a2w1  = (const float*)d_in[18];
    const float* a2b1  = (const float*)d_in[19];
    const float* a2w2  = (const float*)d_in[20];
    const float* a2b2  = (const float*)d_in[21];
    const float* tw1   = (const float*)d_in[22];
    const float* tb1   = (const float*)d_in[23];
    const float* tw2   = (const float*)d_in[24];
    const float* tb2   = (const float*)d_in[25];
    float* out = (float*)d_out;

    char* wsb = (char*)d_ws; size_t off = 0;
    auto alloc = [&](size_t bytes)->char*{
        char* p = wsb + off; off = (off + bytes + 511) & ~(size_t)511; return p;
    };
    float*          embW  = (float*)alloc((size_t)VOC*256*4);
    float*          diff  = (float*)alloc((size_t)BATCH*NOBJ*4*4);
    float*          pre1  = (float*)alloc((size_t)BATCH*NOBJ*32*4);
    float*          pre2  = (float*)alloc((size_t)BATCH*NOBJ*32*4);
    _Float16*       attLp = (_Float16*)alloc((size_t)256*64*2);
    _Float16*       attHp = (_Float16*)alloc((size_t)256*64*2);
    _Float16*       wLhap = (_Float16*)alloc((size_t)256*64*2);
    _Float16*       wLhlp = (_Float16*)alloc((size_t)256*64*2);
    _Float16*       Weffp = (_Float16*)alloc((size_t)256*32*2);
    _Float16*       w1fp  = (_Float16*)alloc((size_t)64*64*2);
    float*          biasL2= (float*)alloc(256*4);
    float*          fcb   = (float*)alloc((size_t)NPAD*4);
    unsigned short* hhist = (unsigned short*)alloc((size_t)NROWS*64*2);
    unsigned short* fragB = (unsigned short*)alloc((size_t)NTILE*2*64*8*2);

    // prep
    k_pre    <<<(BATCH*NOBJ+255)/256, 256, 0, stream>>>(prev, fin, a1w1, a1b1, a2w1, a2b1, diff, pre1, pre2);
    k_embw   <<<VOC, 256, 0, stream>>>(embed, Wia, bia, bha, embW);
    k_packrow<<<64, 256, 0, stream>>>(Wia, attLp, 128, 0,  64, 256*64);   // W_ih_att[:, :64]  (h_lang)
    k_packrow<<<64, 256, 0, stream>>>(Wha, attHp,  64, 0,  64, 256*64);   // W_hh_att          (h_att)
    k_packrow<<<64, 256, 0, stream>>>(Wil, wLhap, 128, 64, 64, 256*64);   // W_ih_lang[:,64:]  (h_att)
    k_packrow<<<64, 256, 0, stream>>>(Whl, wLhlp,  64, 0,  64, 256*64);   // W_hh_lang         (h_lang)
    k_packrow<<<8,  256, 0, stream>>>(a1w1, w1fp,       68, 0, 64, 32*64);// att1 w1[:, :64]
    k_packrow<<<8,  256, 0, stream>>>(a2w1, w1fp+32*64, 68, 0, 64, 32*64);// att2 w1[:, :64]
    k_weff   <<<1, 256, 0, stream>>>(Wil, tw2, tb2, bil, bhl, Weffp, biasL2);
    k_fcbpad <<<(NPAD+255)/256, 256, 0, stream>>>(fcbi, fcb);
    k_fragb  <<<63, 256, 0, stream>>>(fcw, fragB);

    // recurrent scan: 4 batch rows per block, quarter-row weight registers
    k_recur<<<BATCH/4, 1024, 0, stream>>>(inst, embW, diff, prev, pre1, pre2,
                                          attLp, attHp, wLhap, wLhlp, Weffp, biasL2, w1fp,
                                          a1w2, a1b2, a2w2, a2b2, tw1, tb1, hhist);

    // big projection + log_softmax
    k_fc<<<NROWS/16, 256, 0, stream>>>(hhist, fragB, fcb, out);
}